// Round 1
// baseline (3978.796 us; speedup 1.0000x reference)
//
#include <hip/hip_runtime.h>
#include <stdint.h>

// S=64, B=64, C=H=E=512, V=32000, steps T=48
// Strategy:
//  Phase 0 (parallel precompute): bf16 weight conversion, W_comb = W_ih1@W_ctx2hid,
//    mean/mix + h0, ctx_proj = ctx@W_ctx2ctx^T, gi0_all = emb[y[:-1]]@W_ih0^T + b_ih0
//  Phase 1 (48 sequential steps, 4 small kernels each): gru0 -> q -> attention -> gru1
//    (gi1 uses precomputed W_comb; logit deferred). h2 states stored (3072x512).
//  Phase 2: logit = tanh(h2_all@W_hid2out^T+b) ; sumexp via one batched
//    3072x32000x512 bf16 GEMM with fused exp-row-sum; target-dot + loss reduce.

using bf16x8 = __attribute__((ext_vector_type(8))) short;
using f32x4  = __attribute__((ext_vector_type(4))) float;
using s16x4  = __attribute__((ext_vector_type(4))) short;

#define DI __device__ __forceinline__

DI short f2bf(float x){
  union { float f; uint32_t u; } v; v.f = x;
  uint32_t r = (v.u + 0x7FFFu + ((v.u >> 16) & 1u)) >> 16;
  return (short)r;
}
DI float sigm(float x){ return __fdividef(1.f, 1.f + __expf(-x)); }
DI float ftanh(float x){ return 1.f - __fdividef(2.f, __expf(2.f*x) + 1.f); }
DI float wsum(float v){
  #pragma unroll
  for (int m = 32; m > 0; m >>= 1) v += __shfl_xor(v, m, 64);
  return v;
}
DI f32x4 mfma16(bf16x8 a, bf16x8 b, f32x4 c){
  return __builtin_amdgcn_mfma_f32_16x16x32_bf16(a, b, c, 0, 0, 0);
}
// A fragment: lane holds A[m0 + (lane&15)][k0 + (lane>>4)*8 + j], fp32 src -> bf16
DI bf16x8 load_a32(const float* __restrict__ A, int ld, int m0, int k0, int lane){
  const float* p = A + (size_t)(m0 + (lane & 15)) * ld + k0 + ((lane >> 4) << 3);
  bf16x8 f;
  #pragma unroll
  for (int j = 0; j < 8; ++j) f[j] = f2bf(p[j]);
  return f;
}
// B fragment for C = A @ W^T (W row-major NxK bf16): lane holds W[n0+(lane&15)][k0+(lane>>4)*8+j]
DI bf16x8 load_b16(const short* __restrict__ W, int ld, int n0, int k0, int lane){
  const short* p = W + (size_t)(n0 + (lane & 15)) * ld + k0 + ((lane >> 4) << 3);
  return *(const bf16x8*)p;
}

// ---------------- elementwise / prep kernels ----------------

__global__ __launch_bounds__(256) void k_cvt(const float4* __restrict__ s, s16x4* __restrict__ d, int n4){
  int i = blockIdx.x * 256 + threadIdx.x;
  if (i >= n4) return;
  float4 v = s[i];
  s16x4 o; o[0] = f2bf(v.x); o[1] = f2bf(v.y); o[2] = f2bf(v.z); o[3] = f2bf(v.w);
  d[i] = o;
}

// WT[c*512+h] = bf16(W[h*512+c])  (transpose+convert, 512x512)
__global__ __launch_bounds__(256) void k_tc(const float* __restrict__ W, short* __restrict__ WT){
  int i = blockIdx.x * 256 + threadIdx.x;
  int c = i >> 9, h = i & 511;
  WT[i] = f2bf(W[h * 512 + c]);
}

__global__ __launch_bounds__(256) void k_zero(float* __restrict__ p, int n){
  int i = blockIdx.x * 256 + threadIdx.x;
  if (i < n) p[i] = 0.f;
}

// mixed[b,c] = 0.5*(sum_s ctx[s,b,c]/sum_s mask[s,b]) + 0.5*txt[b,c]
__global__ __launch_bounds__(256) void k_meanmix(const float* __restrict__ ctx, const float* __restrict__ mask,
                                                 const float* __restrict__ txt, float* __restrict__ mixed){
  int i = blockIdx.x * 256 + threadIdx.x;   // 0..32767
  int b = i >> 9, c = i & 511;
  float s = 0.f;
  for (int t = 0; t < 64; ++t) s += ctx[(size_t)(t * 64 + b) * 512 + c];
  float dn = 0.f;
  for (int t = 0; t < 64; ++t) dn += mask[t * 64 + b];
  mixed[i] = 0.5f * (s / dn) + 0.5f * txt[i];
}

// ---------------- generic wave-tile GEMMs (K = 512) ----------------

// C[M,N] = act(A[M,512] @ W[N,512]^T), fp32 out. grid = M/16 * N/16 / 4 blocks of 256.
__global__ __launch_bounds__(256) void k_gemm_bt(const float* __restrict__ A, const short* __restrict__ W,
                                                 float* __restrict__ C, int N, int act){
  int wg = blockIdx.x * 4 + (threadIdx.x >> 6);
  int lane = threadIdx.x & 63;
  int ntiles = N >> 4;
  int mt = wg / ntiles, nt = wg - mt * ntiles;
  int m0 = mt << 4, n0 = nt << 4;
  f32x4 acc = {0.f, 0.f, 0.f, 0.f};
  for (int k = 0; k < 512; k += 32)
    acc = mfma16(load_a32(A, 512, m0, k, lane), load_b16(W, 512, n0, k, lane), acc);
  int col = n0 + (lane & 15);
  int r0 = m0 + ((lane >> 4) << 2);
  #pragma unroll
  for (int r = 0; r < 4; ++r){
    float v = acc[r];
    if (act) v = ftanh(v);
    C[(size_t)(r0 + r) * N + col] = v;
  }
}

// same, bf16 out (for W_comb)
__global__ __launch_bounds__(256) void k_gemm_bt_obf(const float* __restrict__ A, const short* __restrict__ W,
                                                     short* __restrict__ C, int N){
  int wg = blockIdx.x * 4 + (threadIdx.x >> 6);
  int lane = threadIdx.x & 63;
  int ntiles = N >> 4;
  int mt = wg / ntiles, nt = wg - mt * ntiles;
  int m0 = mt << 4, n0 = nt << 4;
  f32x4 acc = {0.f, 0.f, 0.f, 0.f};
  for (int k = 0; k < 512; k += 32)
    acc = mfma16(load_a32(A, 512, m0, k, lane), load_b16(W, 512, n0, k, lane), acc);
  int col = n0 + (lane & 15);
  int r0 = m0 + ((lane >> 4) << 2);
  #pragma unroll
  for (int r = 0; r < 4; ++r)
    C[(size_t)(r0 + r) * N + col] = f2bf(acc[r]);
}

// gi0_all[3072,1536] = emb[y[0..3071]] @ W_ih0^T + b_ih0
__global__ __launch_bounds__(256) void k_gi0(const int* __restrict__ y, const float* __restrict__ emb,
                                             const short* __restrict__ W, const float* __restrict__ bias,
                                             float* __restrict__ C){
  int wg = blockIdx.x * 4 + (threadIdx.x >> 6);
  int lane = threadIdx.x & 63;
  int mt = wg / 96, nt = wg - mt * 96;
  int m0 = mt << 4, n0 = nt << 4;
  int yr = y[m0 + (lane & 15)];
  const float* arow = emb + (size_t)yr * 512;
  f32x4 acc = {0.f, 0.f, 0.f, 0.f};
  for (int k = 0; k < 512; k += 32){
    const float* p = arow + k + ((lane >> 4) << 3);
    bf16x8 a;
    #pragma unroll
    for (int j = 0; j < 8; ++j) a[j] = f2bf(p[j]);
    acc = mfma16(a, load_b16(W, 512, n0, k, lane), acc);
  }
  int col = n0 + (lane & 15);
  int r0 = m0 + ((lane >> 4) << 2);
  #pragma unroll
  for (int r = 0; r < 4; ++r)
    C[(size_t)(r0 + r) * 1536 + col] = acc[r] + bias[col];
}

// ---------------- recurrent-step kernels ----------------

// h1 = GRU(gi (precomputed, incl. b_ih), gh = h@Whh^T + b_hh, h).  grid 32x256.
__global__ __launch_bounds__(256) void k_gru0(const float* __restrict__ h, const float* __restrict__ gi,
                                              const short* __restrict__ Whh, const float* __restrict__ bhh,
                                              float* __restrict__ h1){
  int wg = blockIdx.x * 4 + (threadIdx.x >> 6);   // 0..127
  int lane = threadIdx.x & 63;
  int m0 = (wg >> 5) << 4, j0 = (wg & 31) << 4;
  f32x4 aR = {0,0,0,0}, aZ = {0,0,0,0}, aN = {0,0,0,0};
  for (int k = 0; k < 512; k += 32){
    bf16x8 a = load_a32(h, 512, m0, k, lane);
    aR = mfma16(a, load_b16(Whh, 512, j0,        k, lane), aR);
    aZ = mfma16(a, load_b16(Whh, 512, 512 + j0,  k, lane), aZ);
    aN = mfma16(a, load_b16(Whh, 512, 1024 + j0, k, lane), aN);
  }
  int col = j0 + (lane & 15);
  int r0 = m0 + ((lane >> 4) << 2);
  #pragma unroll
  for (int r = 0; r < 4; ++r){
    int b = r0 + r;
    const float* gib = gi + (size_t)b * 1536;
    float gr = aR[r] + bhh[col];
    float gz = aZ[r] + bhh[512 + col];
    float gn = aN[r] + bhh[1024 + col];
    float rr = sigm(gib[col] + gr);
    float zz = sigm(gib[512 + col] + gz);
    float nn = ftanh(gib[1024 + col] + rr * gn);
    float hp = h[(size_t)b * 512 + col];
    h1[(size_t)b * 512 + col] = (1.f - zz) * nn + zz * hp;
  }
}

// h2 = GRU(gi1 = catt@Wcomb^T + bih1, gh1 = h1@Whh1^T + bhh1, h1).  grid 32x256.
__global__ __launch_bounds__(256) void k_gru1(const float* __restrict__ h1, const float* __restrict__ catt,
                                              const short* __restrict__ Wcomb, const short* __restrict__ Whh1,
                                              const float* __restrict__ bih1, const float* __restrict__ bhh1,
                                              float* __restrict__ h2){
  int wg = blockIdx.x * 4 + (threadIdx.x >> 6);
  int lane = threadIdx.x & 63;
  int m0 = (wg >> 5) << 4, j0 = (wg & 31) << 4;
  f32x4 iR = {0,0,0,0}, iZ = {0,0,0,0}, iN = {0,0,0,0};
  f32x4 hR = {0,0,0,0}, hZ = {0,0,0,0}, hN = {0,0,0,0};
  for (int k = 0; k < 512; k += 32){
    bf16x8 a1 = load_a32(catt, 512, m0, k, lane);
    bf16x8 a2 = load_a32(h1,   512, m0, k, lane);
    iR = mfma16(a1, load_b16(Wcomb, 512, j0,        k, lane), iR);
    iZ = mfma16(a1, load_b16(Wcomb, 512, 512 + j0,  k, lane), iZ);
    iN = mfma16(a1, load_b16(Wcomb, 512, 1024 + j0, k, lane), iN);
    hR = mfma16(a2, load_b16(Whh1, 512, j0,        k, lane), hR);
    hZ = mfma16(a2, load_b16(Whh1, 512, 512 + j0,  k, lane), hZ);
    hN = mfma16(a2, load_b16(Whh1, 512, 1024 + j0, k, lane), hN);
  }
  int col = j0 + (lane & 15);
  int r0 = m0 + ((lane >> 4) << 2);
  #pragma unroll
  for (int r = 0; r < 4; ++r){
    int b = r0 + r;
    float gir = iR[r] + bih1[col];
    float giz = iZ[r] + bih1[512 + col];
    float gin = iN[r] + bih1[1024 + col];
    float ghr = hR[r] + bhh1[col];
    float ghz = hZ[r] + bhh1[512 + col];
    float ghn = hN[r] + bhh1[1024 + col];
    float rr = sigm(gir + ghr);
    float zz = sigm(giz + ghz);
    float nn = ftanh(gin + rr * ghn);
    float hp = h1[(size_t)b * 512 + col];
    h2[(size_t)b * 512 + col] = (1.f - zz) * nn + zz * hp;
  }
}

// per-b attention: scores -> softmax -> ctx_att.  grid 64x256 (one wg per b).
__global__ __launch_bounds__(256) void k_attn(const float* __restrict__ q, const float* __restrict__ ctx_proj,
                                              const float* __restrict__ ctx, const float* __restrict__ mask,
                                              const float* __restrict__ wmlp, float* __restrict__ catt){
  __shared__ float qs[512], wm[512], sc[64], al[64];
  int b = blockIdx.x;
  int tid = threadIdx.x;
  int w = tid >> 6, lane = tid & 63;
  qs[tid] = q[(size_t)b * 512 + tid];       qs[tid + 256] = q[(size_t)b * 512 + tid + 256];
  wm[tid] = wmlp[tid];                      wm[tid + 256] = wmlp[tid + 256];
  __syncthreads();
  for (int i = 0; i < 16; ++i){
    int s = w * 16 + i;
    const float* cp = ctx_proj + (size_t)(s * 64 + b) * 512 + lane * 8;
    float p = 0.f;
    #pragma unroll
    for (int j = 0; j < 8; ++j){
      int m = lane * 8 + j;
      p += ftanh(cp[j] + qs[m]) * wm[m];
    }
    p = wsum(p);
    if (lane == 0) sc[s] = p;
  }
  __syncthreads();
  if (tid < 64){
    float mk = mask[tid * 64 + b];
    float v = (mk > 0.f) ? sc[tid] : -100000000.0f;
    float mx = v;
    #pragma unroll
    for (int m = 32; m > 0; m >>= 1) mx = fmaxf(mx, __shfl_xor(mx, m, 64));
    float e = __expf(v - mx);
    float se = e;
    #pragma unroll
    for (int m = 32; m > 0; m >>= 1) se += __shfl_xor(se, m, 64);
    al[tid] = e / se;
  }
  __syncthreads();
  for (int c = tid; c < 512; c += 256){
    float a = 0.f;
    for (int s = 0; s < 64; ++s) a += al[s] * ctx[(size_t)(s * 64 + b) * 512 + c];
    catt[(size_t)b * 512 + c] = a;
  }
}

// ---------------- phase 2 ----------------

// tl = tanh(h2_all @ W_hid2out^T + b), stored bf16 + fp32.  grid 1536x256.
__global__ __launch_bounds__(256) void k_logit(const float* __restrict__ A, const short* __restrict__ W,
                                               const float* __restrict__ bias, short* __restrict__ tlb,
                                               float* __restrict__ tlf){
  int wg = blockIdx.x * 4 + (threadIdx.x >> 6);
  int lane = threadIdx.x & 63;
  int mt = wg >> 5, nt = wg & 31;
  int m0 = mt << 4, n0 = nt << 4;
  f32x4 acc = {0.f, 0.f, 0.f, 0.f};
  for (int k = 0; k < 512; k += 32)
    acc = mfma16(load_a32(A, 512, m0, k, lane), load_b16(W, 512, n0, k, lane), acc);
  int col = n0 + (lane & 15);
  int r0 = m0 + ((lane >> 4) << 2);
  #pragma unroll
  for (int r = 0; r < 4; ++r){
    float v = ftanh(acc[r] + bias[col]);
    size_t o = (size_t)(r0 + r) * 512 + col;
    tlf[o] = v; tlb[o] = f2bf(v);
  }
}

// sumexp[row] += sum_n exp(tl[row]@Wop[n] + bop[n]); 128x128 LDS-tiled bf16 GEMM.
// A: 3072x512 bf16, B: 32000x512 bf16. grid 24*250=6000, block 256.
__global__ __launch_bounds__(256) void k_sumexp(const short* __restrict__ A, const short* __restrict__ B,
                                                const float* __restrict__ bias, float* __restrict__ sumexp){
  __shared__ short lA[128 * 32];
  __shared__ short lB[128 * 32];
  int bm = blockIdx.x % 24, bn = blockIdx.x / 24;
  int m0 = bm * 128, n0 = bn * 128;
  int tid = threadIdx.x, w = tid >> 6, lane = tid & 63;
  int mq = (w >> 1) * 64, nq = (w & 1) * 64;
  f32x4 acc[4][4];
  #pragma unroll
  for (int i = 0; i < 4; ++i)
    #pragma unroll
    for (int j = 0; j < 4; ++j) acc[i][j] = (f32x4){0.f, 0.f, 0.f, 0.f};

  for (int k0 = 0; k0 < 512; k0 += 32){
    __syncthreads();
    #pragma unroll
    for (int i = 0; i < 2; ++i){
      int idx = tid * 8 + i * 2048;           // halfword index into 128x32 tile
      int row = idx >> 5, col = idx & 31;
      *(bf16x8*)&lA[idx] = *(const bf16x8*)(A + (size_t)(m0 + row) * 512 + k0 + col);
      *(bf16x8*)&lB[idx] = *(const bf16x8*)(B + (size_t)(n0 + row) * 512 + k0 + col);
    }
    __syncthreads();
    bf16x8 af[4], bf[4];
    #pragma unroll
    for (int x = 0; x < 4; ++x){
      af[x] = *(const bf16x8*)&lA[(mq + x * 16 + (lane & 15)) * 32 + ((lane >> 4) << 3)];
      bf[x] = *(const bf16x8*)&lB[(nq + x * 16 + (lane & 15)) * 32 + ((lane >> 4) << 3)];
    }
    #pragma unroll
    for (int mi = 0; mi < 4; ++mi)
      #pragma unroll
      for (int ni = 0; ni < 4; ++ni)
        acc[mi][ni] = mfma16(af[mi], bf[ni], acc[mi][ni]);
  }

  #pragma unroll
  for (int mi = 0; mi < 4; ++mi){
    #pragma unroll
    for (int r = 0; r < 4; ++r){
      float e = 0.f;
      #pragma unroll
      for (int ni = 0; ni < 4; ++ni){
        int col = n0 + nq + ni * 16 + (lane & 15);
        e += __expf(acc[mi][ni][r] + bias[col]);
      }
      e += __shfl_xor(e, 1, 64); e += __shfl_xor(e, 2, 64);
      e += __shfl_xor(e, 4, 64); e += __shfl_xor(e, 8, 64);
      if ((lane & 15) == 0){
        int row = m0 + mq + mi * 16 + ((lane >> 4) << 2) + r;
        atomicAdd(&sumexp[row], e);
      }
    }
  }
}

// per-row target dot + loss accumulation. grid 48x256 (one wg per step).
__global__ __launch_bounds__(256) void k_loss(const float* __restrict__ tlf, const float* __restrict__ Wop,
                                              const float* __restrict__ bop, const int* __restrict__ y,
                                              const float* __restrict__ sumexp, float* __restrict__ loss){
  int step = blockIdx.x;
  int w = threadIdx.x >> 6, lane = threadIdx.x & 63;
  __shared__ float accw[4];
  float part = 0.f;
  for (int b = w; b < 64; b += 4){
    int row = step * 64 + b;
    int t = y[(step + 1) * 64 + b];
    if (t != 0){
      const float* a = tlf + (size_t)row * 512 + lane * 8;
      const float* wr = Wop + (size_t)t * 512 + lane * 8;
      float d = 0.f;
      #pragma unroll
      for (int j = 0; j < 8; ++j) d += a[j] * wr[j];
      d = wsum(d);
      if (lane == 0) part += d + bop[t] - __logf(sumexp[row]);
    }
  }
  if (lane == 0) accw[w] = part;
  __syncthreads();
  if (threadIdx.x == 0) atomicAdd(loss, -(accw[0] + accw[1] + accw[2] + accw[3]));
}

__global__ void k_final(const float* __restrict__ loss, float* __restrict__ out){
  if (threadIdx.x == 0 && blockIdx.x == 0) out[0] = loss[0];
}

// ---------------- host launch ----------------

extern "C" void kernel_launch(void* const* d_in, const int* in_sizes, int n_in,
                              void* d_out, int out_size, void* d_ws, size_t ws_size,
                              hipStream_t stream) {
  const float* ctx       = (const float*)d_in[0];
  const float* ctx_mask  = (const float*)d_in[1];
  const float* txt_ctx   = (const float*)d_in[2];
  const int*   y         = (const int*)d_in[3];
  const float* emb       = (const float*)d_in[4];
  const float* W_ctx2ctx = (const float*)d_in[5];
  const float* W_hid2ctx = (const float*)d_in[6];
  const float* w_mlp     = (const float*)d_in[7];
  const float* W_ctx2hid = (const float*)d_in[8];
  const float* W_dec_init= (const float*)d_in[9];
  const float* W_ih0     = (const float*)d_in[10];
  const float* W_hh0     = (const float*)d_in[11];
  const float* b_ih0     = (const float*)d_in[12];
  const float* b_hh0     = (const float*)d_in[13];
  const float* W_ih1     = (const float*)d_in[14];
  const float* W_hh1     = (const float*)d_in[15];
  const float* b_ih1     = (const float*)d_in[16];
  const float* b_hh1     = (const float*)d_in[17];
  const float* W_hid2out = (const float*)d_in[18];
  const float* b_hid2out = (const float*)d_in[19];
  const float* W_out2prob= (const float*)d_in[20];
  const float* b_out2prob= (const float*)d_in[21];
  float* out = (float*)d_out;

  char* p = (char*)d_ws;
  auto alloc = [&](size_t n){ char* r = p; p += (n + 255) & ~(size_t)255; return r; };
  short* Wb_hh0     = (short*)alloc((size_t)1536 * 512 * 2);
  short* Wb_hid2ctx = (short*)alloc((size_t)512 * 512 * 2);
  short* Wb_hh1     = (short*)alloc((size_t)1536 * 512 * 2);
  short* Wb_hid2out = (short*)alloc((size_t)512 * 512 * 2);
  short* Wb_dec     = (short*)alloc((size_t)512 * 512 * 2);
  short* Wb_c2c     = (short*)alloc((size_t)512 * 512 * 2);
  short* Wb_ih0     = (short*)alloc((size_t)1536 * 512 * 2);
  short* Wb_o2p     = (short*)alloc((size_t)32000 * 512 * 2);
  short* WctT       = (short*)alloc((size_t)512 * 512 * 2);
  short* Wb_comb    = (short*)alloc((size_t)1536 * 512 * 2);
  float* ctx_proj   = (float*)alloc((size_t)4096 * 512 * 4);
  float* gi0_all    = (float*)alloc((size_t)3072 * 1536 * 4);
  float* mixed      = (float*)alloc((size_t)64 * 512 * 4);
  float* h0buf      = (float*)alloc((size_t)64 * 512 * 4);
  float* h1buf      = (float*)alloc((size_t)64 * 512 * 4);
  float* qbuf       = (float*)alloc((size_t)64 * 512 * 4);
  float* cattbuf    = (float*)alloc((size_t)64 * 512 * 4);
  float* h2_all     = (float*)alloc((size_t)3072 * 512 * 4);
  short* tl_bf      = (short*)alloc((size_t)3072 * 512 * 2);
  float* tl_f       = (float*)alloc((size_t)3072 * 512 * 4);
  float* sumexp     = (float*)alloc((size_t)3073 * 4);
  float* lossbuf    = sumexp + 3072;

  dim3 blk(256);
  // ---- phase 0 ----
  auto cvt = [&](const float* s, short* d, size_t n){
    int n4 = (int)(n / 4);
    k_cvt<<<dim3((n4 + 255) / 256), blk, 0, stream>>>((const float4*)s, (s16x4*)d, n4);
  };
  cvt(W_hh0, Wb_hh0, 1536 * 512);
  cvt(W_hid2ctx, Wb_hid2ctx, 512 * 512);
  cvt(W_hh1, Wb_hh1, 1536 * 512);
  cvt(W_hid2out, Wb_hid2out, 512 * 512);
  cvt(W_dec_init, Wb_dec, 512 * 512);
  cvt(W_ctx2ctx, Wb_c2c, 512 * 512);
  cvt(W_ih0, Wb_ih0, 1536 * 512);
  cvt(W_out2prob, Wb_o2p, (size_t)32000 * 512);
  k_tc<<<dim3(1024), blk, 0, stream>>>(W_ctx2hid, WctT);
  k_gemm_bt_obf<<<dim3(768), blk, 0, stream>>>(W_ih1, WctT, Wb_comb, 512);   // W_comb 1536x512
  k_meanmix<<<dim3(128), blk, 0, stream>>>(ctx, ctx_mask, txt_ctx, mixed);
  k_gemm_bt<<<dim3(32), blk, 0, stream>>>(mixed, Wb_dec, h0buf, 512, 1);     // h0 = tanh(.)
  k_gemm_bt<<<dim3(2048), blk, 0, stream>>>(ctx, Wb_c2c, ctx_proj, 512, 0);  // ctx_proj
  k_gi0<<<dim3(4608), blk, 0, stream>>>(y, emb, Wb_ih0, b_ih0, gi0_all);
  k_zero<<<dim3(13), blk, 0, stream>>>(sumexp, 3073);

  // ---- phase 1: 48 sequential steps ----
  for (int t = 0; t < 48; ++t){
    const float* hprev = (t == 0) ? h0buf : (h2_all + (size_t)(t - 1) * 64 * 512);
    k_gru0<<<dim3(32), blk, 0, stream>>>(hprev, gi0_all + (size_t)t * 64 * 1536, Wb_hh0, b_hh0, h1buf);
    k_gemm_bt<<<dim3(32), blk, 0, stream>>>(h1buf, Wb_hid2ctx, qbuf, 512, 0);
    k_attn<<<dim3(64), blk, 0, stream>>>(qbuf, ctx_proj, ctx, ctx_mask, w_mlp, cattbuf);
    k_gru1<<<dim3(32), blk, 0, stream>>>(h1buf, cattbuf, Wb_comb, Wb_hh1, b_ih1, b_hh1,
                                         h2_all + (size_t)t * 64 * 512);
  }

  // ---- phase 2 ----
  k_logit<<<dim3(1536), blk, 0, stream>>>(h2_all, Wb_hid2out, b_hid2out, tl_bf, tl_f);
  k_sumexp<<<dim3(6000), blk, 0, stream>>>(tl_bf, Wb_o2p, b_out2prob, sumexp);
  k_loss<<<dim3(48), blk, 0, stream>>>(tl_f, W_out2prob, b_out2prob, y, sumexp, lossbuf);
  k_final<<<dim3(1), blk, 0, stream>>>(lossbuf, out);
}